// Round 1
// baseline (413.885 us; speedup 1.0000x reference)
//
#include <hip/hip_runtime.h>

#define NB 32
#define NT 2048
#define ND 1024
#define NU 1024
#define NM (NB*NT)   // 65536 rows

using f32x4 = __attribute__((ext_vector_type(4))) float;
using s16x8 = __attribute__((ext_vector_type(8))) short;

__device__ __forceinline__ unsigned short f2bf(float f) {
  unsigned u = __builtin_bit_cast(unsigned, f);
  u = u + 0x7fffu + ((u >> 16) & 1u);   // round-to-nearest-even
  return (unsigned short)(u >> 16);
}

__device__ __forceinline__ void gload_lds16(const void* g, void* l) {
  __builtin_amdgcn_global_load_lds(
      (const __attribute__((address_space(1))) unsigned int*)g,
      (__attribute__((address_space(3))) unsigned int*)l, 16, 0, 0);
}

__device__ __forceinline__ float tanh_fast(float x) {
  float e = __expf(2.0f * x);
  return 1.0f - 2.0f * __builtin_amdgcn_rcpf(e + 1.0f);
}

// add2[b][u] = query[b]·W1_k[:,u] + W1_b[u] + W2_b[u]
__global__ void k_qproj(const float* __restrict__ q, const float* __restrict__ W1,
                        const float* __restrict__ W1b, const float* __restrict__ W2b,
                        float* __restrict__ add2) {
  int u = blockIdx.x * 256 + threadIdx.x;
  int b = blockIdx.y;
  const float* qr = q + (b << 10);
  float s = 0.f;
#pragma unroll 8
  for (int d = 0; d < ND; ++d) s = fmaf(qr[d], W1[d * NU + u], s);
  add2[(b << 10) + u] = s + W1b[u] + W2b[u];
}

// W2_k [D][U] f32 -> W2t [U][D] bf16
__global__ void k_w2t(const float* __restrict__ W2, unsigned short* __restrict__ W2t) {
  __shared__ unsigned short tile[64][65];
  int bu = blockIdx.x * 64, bd = blockIdx.y * 64;
  int x = threadIdx.x & 63, y4 = threadIdx.x >> 6;
#pragma unroll
  for (int r = 0; r < 16; ++r) {
    int dl = y4 * 16 + r;
    tile[x][dl] = f2bf(W2[(size_t)(bd + dl) * NU + bu + x]);
  }
  __syncthreads();
#pragma unroll
  for (int r = 0; r < 16; ++r) {
    int ul = y4 * 16 + r;
    W2t[(size_t)(bu + ul) * ND + bd + x] = tile[ul][x];
  }
}

// values f32 -> bf16 (big-ws path)
__global__ void k_cvt_values(const float4* __restrict__ v, ushort4* __restrict__ o) {
  const int n4 = NM * ND / 4;
  for (int i = blockIdx.x * blockDim.x + threadIdx.x; i < n4; i += gridDim.x * blockDim.x) {
    float4 f = v[i];
    ushort4 h;
    h.x = f2bf(f.x); h.y = f2bf(f.y); h.z = f2bf(f.z); h.w = f2bf(f.w);
    o[i] = h;
  }
}

// Fused score GEMM: score_part[ntile][row] = sum_{u in ntile} tanh(vp+add2)*Vk[u]
template<bool BIG>
__global__ __launch_bounds__(256) void k_score_gemm(
    const float* __restrict__ values,
    const unsigned short* __restrict__ vbf,
    const unsigned short* __restrict__ W2t,
    const float* __restrict__ add2,
    const float* __restrict__ Vk,
    float* __restrict__ score_part) {
  constexpr int ASTR = BIG ? 64 : 72;   // LDS A row stride (elems); pad only on reg-staged path
  __shared__ unsigned short sA[128 * 72];
  __shared__ unsigned short sB[128 * 64];
  const int tid = threadIdx.x;
  const int w = tid >> 6, lane = tid & 63;
  const int wr = w >> 1, wc = w & 1;
  const int l15 = lane & 15, lg = lane >> 4;
  const int r8 = lane >> 3, c8 = lane & 7;

  // XCD-aware swizzle: 8 consecutive slots on one XCD walk ntile fastest -> A strip L2-resident
  const int L = blockIdx.x;
  const int mtile = (L & 7) * 64 + ((L >> 3) >> 3);
  const int ntile = (L >> 3) & 7;

  f32x4 acc[4][4] = {};

  for (int kk = 0; kk < 16; ++kk) {
    const int k0 = kk * 64;
#pragma unroll
    for (int i = 0; i < 4; ++i) {   // B tile: 128 n x 64 k bf16 via global_load_lds
      int nl = (w * 4 + i) * 8 + r8;
      gload_lds16(W2t + ((size_t)(ntile * 128 + nl) << 10) + k0 + c8 * 8,
                  sB + (w * 4 + i) * 512);
    }
    if (BIG) {
#pragma unroll
      for (int i = 0; i < 4; ++i) {
        int rl = (w * 4 + i) * 8 + r8;
        gload_lds16(vbf + ((size_t)(mtile * 128 + rl) << 10) + k0 + c8 * 8,
                    sA + (w * 4 + i) * 512);
      }
    } else {
#pragma unroll
      for (int i = 0; i < 8; ++i) {  // reg-stage f32 -> bf16
        int idx = tid + (i << 8);
        int row = idx >> 4, kc = idx & 15;
        const float4 f = *(const float4*)(values + ((size_t)(mtile * 128 + row) << 10) + k0 + kc * 4);
        ushort4 h;
        h.x = f2bf(f.x); h.y = f2bf(f.y); h.z = f2bf(f.z); h.w = f2bf(f.w);
        *(ushort4*)(sA + row * ASTR + kc * 4) = h;
      }
    }
    __syncthreads();
#pragma unroll
    for (int ks = 0; ks < 2; ++ks) {
      s16x8 af[4], bfr[4];
#pragma unroll
      for (int m = 0; m < 4; ++m)
        af[m] = *(const s16x8*)(sA + (wr * 64 + m * 16 + l15) * ASTR + ks * 32 + lg * 8);
#pragma unroll
      for (int n = 0; n < 4; ++n)
        bfr[n] = *(const s16x8*)(sB + ((wc * 64 + n * 16 + l15) << 6) + ks * 32 + lg * 8);
#pragma unroll
      for (int m = 0; m < 4; ++m)
#pragma unroll
        for (int n = 0; n < 4; ++n)
          acc[m][n] = __builtin_amdgcn_mfma_f32_16x16x32_bf16(af[m], bfr[n], acc[m][n], 0, 0, 0);
    }
    __syncthreads();
  }

  // Epilogue: x = acc + add2[b][u]; partial row-sum of tanh(x)*Vk[u]
  const int b = (mtile * 128) >> 11;   // block-uniform (128 | 2048)
  float vks[4], adds[4];
#pragma unroll
  for (int n = 0; n < 4; ++n) {
    int u = ntile * 128 + wc * 64 + n * 16 + l15;
    vks[n] = Vk[u];
    adds[n] = add2[(b << 10) + u];
  }
  float rs[4][4];
#pragma unroll
  for (int m = 0; m < 4; ++m) {
#pragma unroll
    for (int j = 0; j < 4; ++j) {
      float s = 0.f;
#pragma unroll
      for (int n = 0; n < 4; ++n) {
        float x = acc[m][n][j] + adds[n];
        s = fmaf(tanh_fast(x), vks[n], s);
      }
#pragma unroll
      for (int off = 1; off < 16; off <<= 1) s += __shfl_xor(s, off);
      rs[m][j] = s;   // C/D: col=l15, row=lg*4+j  -> 16-lane groups share rows
    }
  }
  __syncthreads();
  float* rowsum = (float*)sA;
  if (wc == 0 && l15 == 0) {
#pragma unroll
    for (int m = 0; m < 4; ++m)
#pragma unroll
      for (int j = 0; j < 4; ++j)
        rowsum[wr * 64 + m * 16 + lg * 4 + j] = rs[m][j];
  }
  __syncthreads();
  if (wc == 1 && l15 == 0) {
#pragma unroll
    for (int m = 0; m < 4; ++m)
#pragma unroll
      for (int j = 0; j < 4; ++j)
        rowsum[wr * 64 + m * 16 + lg * 4 + j] += rs[m][j];
  }
  __syncthreads();
  if (tid < 128)
    score_part[((size_t)ntile << 16) + mtile * 128 + tid] = rowsum[tid];
}

// softmax over T per batch; sums the 8 N-tile partials first (deterministic)
__global__ void k_softmax(const float* __restrict__ sp, float* __restrict__ w) {
  __shared__ float redm[4], reds[4];
  int b = blockIdx.x, tid = threadIdx.x;
  float s[8];
  float mx = -1e30f;
#pragma unroll
  for (int i = 0; i < 8; ++i) {
    int t = i * 256 + tid;
    float v = 0.f;
#pragma unroll
    for (int p = 0; p < 8; ++p) v += sp[((size_t)p << 16) + (b << 11) + t];
    s[i] = v;
    mx = fmaxf(mx, v);
  }
#pragma unroll
  for (int o = 1; o < 64; o <<= 1) mx = fmaxf(mx, __shfl_xor(mx, o));
  if ((tid & 63) == 0) redm[tid >> 6] = mx;
  __syncthreads();
  mx = fmaxf(fmaxf(redm[0], redm[1]), fmaxf(redm[2], redm[3]));
  float sum = 0.f;
#pragma unroll
  for (int i = 0; i < 8; ++i) { s[i] = __expf(s[i] - mx); sum += s[i]; }
#pragma unroll
  for (int o = 1; o < 64; o <<= 1) sum += __shfl_xor(sum, o);
  if ((tid & 63) == 0) reds[tid >> 6] = sum;
  __syncthreads();
  float inv = 1.0f / (reds[0] + reds[1] + reds[2] + reds[3]);
#pragma unroll
  for (int i = 0; i < 8; ++i) w[(b << 11) + i * 256 + tid] = s[i] * inv;
}

// context partials: part[tc][b][d] = sum_{t in chunk} w[b][t]*values[b][t][d]
__global__ void k_context(const float* __restrict__ values, const float* __restrict__ wv,
                          float* __restrict__ part) {
  int d = blockIdx.x * 256 + threadIdx.x;
  int b = blockIdx.y, tc = blockIdx.z;
  const float* vb = values + ((size_t)b << 21) + ((size_t)tc << 18) + d;
  const float* wb = wv + (b << 11) + (tc << 8);
  float acc = 0.f;
#pragma unroll 8
  for (int t = 0; t < 256; ++t) acc = fmaf(wb[t], vb[(size_t)t << 10], acc);
  part[(((size_t)tc * NB + b) << 10) + d] = acc;
}

__global__ void k_ctx_reduce(const float* __restrict__ part, float* __restrict__ out) {
  int i = blockIdx.x * 256 + threadIdx.x;  // 32768
  float s = 0.f;
#pragma unroll
  for (int p = 0; p < 8; ++p) s += part[(p << 15) + i];
  out[i] = s;
}

extern "C" void kernel_launch(void* const* d_in, const int* in_sizes, int n_in,
                              void* d_out, int out_size, void* d_ws, size_t ws_size,
                              hipStream_t stream) {
  const float* query  = (const float*)d_in[0];
  const float* values = (const float*)d_in[1];
  const float* W1k    = (const float*)d_in[2];
  const float* W1b    = (const float*)d_in[3];
  const float* W2k    = (const float*)d_in[4];
  const float* W2b    = (const float*)d_in[5];
  const float* Vk     = (const float*)d_in[6];
  // V_b dropped: softmax is shift-invariant.
  float* out = (float*)d_out;
  char* ws = (char*)d_ws;

  size_t off = 0;
  float* add2 = (float*)(ws + off); off += (size_t)NB * NU * 4;          // 128 KB
  float* sp   = (float*)(ws + off); off += (size_t)8 * NM * 4;           // 2 MB
  float* wv   = (float*)(ws + off); off += (size_t)NM * 4;               // 256 KB
  float* ctxp = (float*)(ws + off); off += (size_t)8 * NB * ND * 4;      // 1 MB
  unsigned short* W2t = (unsigned short*)(ws + off); off += (size_t)NU * ND * 2; // 2 MB
  unsigned short* vbf = (unsigned short*)(ws + off);
  size_t need_big = off + (size_t)NM * ND * 2;                           // +128 MB
  bool big = ws_size >= need_big;

  k_qproj<<<dim3(4, 32), 256, 0, stream>>>(query, W1k, W1b, W2b, add2);
  k_w2t<<<dim3(16, 16), 256, 0, stream>>>(W2k, W2t);
  if (big) {
    k_cvt_values<<<dim3(2048), 256, 0, stream>>>((const float4*)values, (ushort4*)vbf);
    k_score_gemm<true><<<dim3(4096), 256, 0, stream>>>(values, vbf, W2t, add2, Vk, sp);
  } else {
    k_score_gemm<false><<<dim3(4096), 256, 0, stream>>>(values, vbf, W2t, add2, Vk, sp);
  }
  k_softmax<<<dim3(32), 256, 0, stream>>>(sp, wv);
  k_context<<<dim3(4, 32, 8), 256, 0, stream>>>(values, wv, ctxp);
  k_ctx_reduce<<<dim3(128), 256, 0, stream>>>(ctxp, out);
}

// Round 2
// 391.530 us; speedup vs baseline: 1.0571x; 1.0571x over previous
//
#include <hip/hip_runtime.h>

#define NB 32
#define NT 2048
#define ND 1024
#define NU 1024
#define NM (NB*NT)   // 65536 rows

using f32x4 = __attribute__((ext_vector_type(4))) float;
using s16x8 = __attribute__((ext_vector_type(8))) short;

__device__ __forceinline__ unsigned short f2bf(float f) {
  unsigned u = __builtin_bit_cast(unsigned, f);
  u = u + 0x7fffu + ((u >> 16) & 1u);   // round-to-nearest-even
  return (unsigned short)(u >> 16);
}

__device__ __forceinline__ void gload_lds16(const void* g, void* l) {
  __builtin_amdgcn_global_load_lds(
      (const __attribute__((address_space(1))) unsigned int*)g,
      (__attribute__((address_space(3))) unsigned int*)l, 16, 0, 0);
}

__device__ __forceinline__ float tanh_fast(float x) {
  float e = __expf(2.0f * x);
  return 1.0f - 2.0f * __builtin_amdgcn_rcpf(e + 1.0f);
}

// add2[b][u] = query[b]·W1_k[:,u] + W1_b[u] + W2_b[u]
__global__ void k_qproj(const float* __restrict__ q, const float* __restrict__ W1,
                        const float* __restrict__ W1b, const float* __restrict__ W2b,
                        float* __restrict__ add2) {
  int u = blockIdx.x * 256 + threadIdx.x;
  int b = blockIdx.y;
  const float* qr = q + (b << 10);
  float s = 0.f;
#pragma unroll 8
  for (int d = 0; d < ND; ++d) s = fmaf(qr[d], W1[d * NU + u], s);
  add2[(b << 10) + u] = s + W1b[u] + W2b[u];
}

// W2_k [D][U] f32 -> W2t [U][D] bf16
__global__ void k_w2t(const float* __restrict__ W2, unsigned short* __restrict__ W2t) {
  __shared__ unsigned short tile[64][65];
  int bu = blockIdx.x * 64, bd = blockIdx.y * 64;
  int x = threadIdx.x & 63, y4 = threadIdx.x >> 6;
#pragma unroll
  for (int r = 0; r < 16; ++r) {
    int dl = y4 * 16 + r;
    tile[x][dl] = f2bf(W2[(size_t)(bd + dl) * NU + bu + x]);
  }
  __syncthreads();
#pragma unroll
  for (int r = 0; r < 16; ++r) {
    int ul = y4 * 16 + r;
    W2t[(size_t)(bu + ul) * ND + bd + x] = tile[ul][x];
  }
}

// values f32 -> bf16 (big-ws path)
__global__ void k_cvt_values(const float4* __restrict__ v, ushort4* __restrict__ o) {
  const int n4 = NM * ND / 4;
  for (int i = blockIdx.x * blockDim.x + threadIdx.x; i < n4; i += gridDim.x * blockDim.x) {
    float4 f = v[i];
    ushort4 h;
    h.x = f2bf(f.x); h.y = f2bf(f.y); h.z = f2bf(f.z); h.w = f2bf(f.w);
    o[i] = h;
  }
}

// Fused score GEMM: score_part[ntile][row] = sum_{u in ntile} tanh(vp+add2)*Vk[u]
// LDS tiles use the T2 XOR swizzle: 16B column-chunk cc of row r lives at
// byte r*128 + (cc ^ (r&7))*16. For gload_lds (linear LDS write) this is done
// by XOR-ing the GLOBAL source chunk (m173 pattern); ds_reads apply same XOR.
template<bool BIG>
__global__ __launch_bounds__(256) void k_score_gemm(
    const float* __restrict__ values,
    const unsigned short* __restrict__ vbf,
    const unsigned short* __restrict__ W2t,
    const float* __restrict__ add2,
    const float* __restrict__ Vk,
    float* __restrict__ score_part) {
  __shared__ unsigned short sA[128 * 64];
  __shared__ unsigned short sB[128 * 64];
  const int tid = threadIdx.x;
  const int w = tid >> 6, lane = tid & 63;
  const int wr = w >> 1, wc = w & 1;
  const int l15 = lane & 15, lg = lane >> 4;
  const int r8 = lane >> 3, c8 = lane & 7;
  const int cs8 = c8 ^ r8;   // pre-swizzled global column chunk (16B units)

  // XCD-aware swizzle: 8 consecutive slots on one XCD walk ntile fastest -> A strip L2-resident
  const int L = blockIdx.x;
  const int mtile = (L & 7) * 64 + ((L >> 3) >> 3);
  const int ntile = (L >> 3) & 7;

  f32x4 acc[4][4] = {};

  for (int kk = 0; kk < 16; ++kk) {
    const int k0 = kk * 64;
#pragma unroll
    for (int i = 0; i < 4; ++i) {   // B tile: 128 n x 64 k bf16 via global_load_lds
      int nl = (w * 4 + i) * 8 + r8;
      gload_lds16(W2t + ((size_t)(ntile * 128 + nl) << 10) + k0 + cs8 * 8,
                  sB + (w * 4 + i) * 512);
    }
    if (BIG) {
#pragma unroll
      for (int i = 0; i < 4; ++i) {
        int rl = (w * 4 + i) * 8 + r8;
        gload_lds16(vbf + ((size_t)(mtile * 128 + rl) << 10) + k0 + cs8 * 8,
                    sA + (w * 4 + i) * 512);
      }
    } else {
#pragma unroll
      for (int i = 0; i < 8; ++i) {  // reg-stage f32 -> bf16 (swizzled ds_write)
        int idx = tid + (i << 8);
        int row = idx >> 4, kc = idx & 15;   // kc: 8B chunks
        const float4 f = *(const float4*)(values + ((size_t)(mtile * 128 + row) << 10) + k0 + kc * 4);
        ushort4 h;
        h.x = f2bf(f.x); h.y = f2bf(f.y); h.z = f2bf(f.z); h.w = f2bf(f.w);
        int cc = (kc >> 1) ^ (row & 7);
        *(ushort4*)(sA + (row << 6) + cc * 8 + (kc & 1) * 4) = h;
      }
    }
    __syncthreads();
#pragma unroll
    for (int ks = 0; ks < 2; ++ks) {
      s16x8 af[4], bfr[4];
#pragma unroll
      for (int m = 0; m < 4; ++m) {
        int row = wr * 64 + m * 16 + l15;
        int cc = (ks * 4 + lg) ^ (l15 & 7);     // row&7 == l15&7
        af[m] = *(const s16x8*)(sA + (row << 6) + cc * 8);
      }
#pragma unroll
      for (int n = 0; n < 4; ++n) {
        int row = wc * 64 + n * 16 + l15;
        int cc = (ks * 4 + lg) ^ (l15 & 7);
        bfr[n] = *(const s16x8*)(sB + (row << 6) + cc * 8);
      }
#pragma unroll
      for (int m = 0; m < 4; ++m)
#pragma unroll
        for (int n = 0; n < 4; ++n)
          acc[m][n] = __builtin_amdgcn_mfma_f32_16x16x32_bf16(af[m], bfr[n], acc[m][n], 0, 0, 0);
    }
    __syncthreads();
  }

  // Epilogue: x = acc + add2[b][u]; partial row-sum of tanh(x)*Vk[u]
  const int b = (mtile * 128) >> 11;   // block-uniform (128 | 2048)
  float vks[4], adds[4];
#pragma unroll
  for (int n = 0; n < 4; ++n) {
    int u = ntile * 128 + wc * 64 + n * 16 + l15;
    vks[n] = Vk[u];
    adds[n] = add2[(b << 10) + u];
  }
  float rs[4][4];
#pragma unroll
  for (int m = 0; m < 4; ++m) {
#pragma unroll
    for (int j = 0; j < 4; ++j) {
      float s = 0.f;
#pragma unroll
      for (int n = 0; n < 4; ++n) {
        float x = acc[m][n][j] + adds[n];
        s = fmaf(tanh_fast(x), vks[n], s);
      }
#pragma unroll
      for (int off = 1; off < 16; off <<= 1) s += __shfl_xor(s, off);
      rs[m][j] = s;   // C/D: col=l15, row=lg*4+j  -> 16-lane groups share rows
    }
  }
  __syncthreads();
  float* rowsum = (float*)sA;
  if (wc == 0 && l15 == 0) {
#pragma unroll
    for (int m = 0; m < 4; ++m)
#pragma unroll
      for (int j = 0; j < 4; ++j)
        rowsum[wr * 64 + m * 16 + lg * 4 + j] = rs[m][j];
  }
  __syncthreads();
  if (wc == 1 && l15 == 0) {
#pragma unroll
    for (int m = 0; m < 4; ++m)
#pragma unroll
      for (int j = 0; j < 4; ++j)
        rowsum[wr * 64 + m * 16 + lg * 4 + j] += rs[m][j];
  }
  __syncthreads();
  if (tid < 128)
    score_part[((size_t)ntile << 16) + mtile * 128 + tid] = rowsum[tid];
}

// softmax over T per batch; sums the 8 N-tile partials first (deterministic)
__global__ void k_softmax(const float* __restrict__ sp, float* __restrict__ w) {
  __shared__ float redm[4], reds[4];
  int b = blockIdx.x, tid = threadIdx.x;
  float s[8];
  float mx = -1e30f;
#pragma unroll
  for (int i = 0; i < 8; ++i) {
    int t = i * 256 + tid;
    float v = 0.f;
#pragma unroll
    for (int p = 0; p < 8; ++p) v += sp[((size_t)p << 16) + (b << 11) + t];
    s[i] = v;
    mx = fmaxf(mx, v);
  }
#pragma unroll
  for (int o = 1; o < 64; o <<= 1) mx = fmaxf(mx, __shfl_xor(mx, o));
  if ((tid & 63) == 0) redm[tid >> 6] = mx;
  __syncthreads();
  mx = fmaxf(fmaxf(redm[0], redm[1]), fmaxf(redm[2], redm[3]));
  float sum = 0.f;
#pragma unroll
  for (int i = 0; i < 8; ++i) { s[i] = __expf(s[i] - mx); sum += s[i]; }
#pragma unroll
  for (int o = 1; o < 64; o <<= 1) sum += __shfl_xor(sum, o);
  if ((tid & 63) == 0) reds[tid >> 6] = sum;
  __syncthreads();
  float inv = 1.0f / (reds[0] + reds[1] + reds[2] + reds[3]);
#pragma unroll
  for (int i = 0; i < 8; ++i) w[(b << 11) + i * 256 + tid] = s[i] * inv;
}

// context partials: part[tc][b][d] = sum_{t in chunk} w[b][t]*values[b][t][d]
__global__ void k_context(const float* __restrict__ values, const float* __restrict__ wv,
                          float* __restrict__ part) {
  int d = blockIdx.x * 256 + threadIdx.x;
  int b = blockIdx.y, tc = blockIdx.z;
  const float* vb = values + ((size_t)b << 21) + ((size_t)tc << 18) + d;
  const float* wb = wv + (b << 11) + (tc << 8);
  float acc = 0.f;
#pragma unroll 8
  for (int t = 0; t < 256; ++t) acc = fmaf(wb[t], vb[(size_t)t << 10], acc);
  part[(((size_t)tc * NB + b) << 10) + d] = acc;
}

__global__ void k_ctx_reduce(const float* __restrict__ part, float* __restrict__ out) {
  int i = blockIdx.x * 256 + threadIdx.x;  // 32768
  float s = 0.f;
#pragma unroll
  for (int p = 0; p < 8; ++p) s += part[(p << 15) + i];
  out[i] = s;
}

extern "C" void kernel_launch(void* const* d_in, const int* in_sizes, int n_in,
                              void* d_out, int out_size, void* d_ws, size_t ws_size,
                              hipStream_t stream) {
  const float* query  = (const float*)d_in[0];
  const float* values = (const float*)d_in[1];
  const float* W1k    = (const float*)d_in[2];
  const float* W1b    = (const float*)d_in[3];
  const float* W2k    = (const float*)d_in[4];
  const float* W2b    = (const float*)d_in[5];
  const float* Vk     = (const float*)d_in[6];
  // V_b dropped: softmax is shift-invariant.
  float* out = (float*)d_out;
  char* ws = (char*)d_ws;

  size_t off = 0;
  float* add2 = (float*)(ws + off); off += (size_t)NB * NU * 4;          // 128 KB
  float* sp   = (float*)(ws + off); off += (size_t)8 * NM * 4;           // 2 MB
  float* wv   = (float*)(ws + off); off += (size_t)NM * 4;               // 256 KB
  float* ctxp = (float*)(ws + off); off += (size_t)8 * NB * ND * 4;      // 1 MB
  unsigned short* W2t = (unsigned short*)(ws + off); off += (size_t)NU * ND * 2; // 2 MB
  unsigned short* vbf = (unsigned short*)(ws + off);
  size_t need_big = off + (size_t)NM * ND * 2;                           // +128 MB
  bool big = ws_size >= need_big;

  k_qproj<<<dim3(4, 32), 256, 0, stream>>>(query, W1k, W1b, W2b, add2);
  k_w2t<<<dim3(16, 16), 256, 0, stream>>>(W2k, W2t);
  if (big) {
    k_cvt_values<<<dim3(2048), 256, 0, stream>>>((const float4*)values, (ushort4*)vbf);
    k_score_gemm<true><<<dim3(4096), 256, 0, stream>>>(values, vbf, W2t, add2, Vk, sp);
  } else {
    k_score_gemm<false><<<dim3(4096), 256, 0, stream>>>(values, vbf, W2t, add2, Vk, sp);
  }
  k_softmax<<<dim3(32), 256, 0, stream>>>(sp, wv);
  k_context<<<dim3(4, 32, 8), 256, 0, stream>>>(values, wv, ctxp);
  k_ctx_reduce<<<dim3(128), 256, 0, stream>>>(ctxp, out);
}

// Round 3
// 359.372 us; speedup vs baseline: 1.1517x; 1.0895x over previous
//
#include <hip/hip_runtime.h>

#define NB 32
#define NT 2048
#define ND 1024
#define NU 1024
#define NM (NB*NT)   // 65536 rows

using f32x4 = __attribute__((ext_vector_type(4))) float;
using s16x8 = __attribute__((ext_vector_type(8))) short;

#define BAR()   asm volatile("s_barrier" ::: "memory")
#define LGKM0() asm volatile("s_waitcnt lgkmcnt(0)" ::: "memory")
#define VMC(n)  asm volatile("s_waitcnt vmcnt(" #n ")" ::: "memory")

__device__ __forceinline__ unsigned short f2bf(float f) {
  unsigned u = __builtin_bit_cast(unsigned, f);
  u = u + 0x7fffu + ((u >> 16) & 1u);   // round-to-nearest-even
  return (unsigned short)(u >> 16);
}

__device__ __forceinline__ void gload_lds16(const void* g, void* l) {
  __builtin_amdgcn_global_load_lds(
      (const __attribute__((address_space(1))) unsigned int*)g,
      (__attribute__((address_space(3))) unsigned int*)l, 16, 0, 0);
}

__device__ __forceinline__ float tanh_fast(float x) {
  float e = __expf(2.0f * x);
  return 1.0f - 2.0f * __builtin_amdgcn_rcpf(e + 1.0f);
}

// Stage one half-tile (128 rows x 64 k bf16 = 16KB) via global_load_lds.
// Global source column-chunk is pre-XOR-swizzled (m173 pattern); LDS dest linear.
// All 8 waves participate: 2 loads/thread.
__device__ __forceinline__ void stage_half(const unsigned short* g, int gk,
                                           unsigned short* l, int w, int r3, int c8s) {
#pragma unroll
  for (int i = 0; i < 2; ++i) {
    int cb = i * 8 + w;
    gload_lds16(g + (((size_t)(cb * 8 + r3)) << 10) + gk + c8s * 8, l + cb * 512);
  }
}

#define MFMA_Q(MB, NBASE) \
  _Pragma("unroll") \
  for (int m = 0; m < 4; ++m) { \
    _Pragma("unroll") \
    for (int n = 0; n < 2; ++n) { \
      _Pragma("unroll") \
      for (int ks = 0; ks < 2; ++ks) \
        acc[(MB) + m][(NBASE) + n] = __builtin_amdgcn_mfma_f32_16x16x32_bf16( \
            fa[m][ks], fb[(NBASE) + n][ks], acc[(MB) + m][(NBASE) + n], 0, 0, 0); \
    } \
  }

// One K-tile (64 k) = 4 phases. Stage stream: ph1: A-h1(kt+1)->buf^1;
// ph2: B-h0(kt+2)->buf; ph3: B-h1(kt+2)->buf; ph4: A-h0(kt+2)->buf; vmcnt(6).
// Region-retirement makes each stage safe (B retired at ph1 lgkm, A at ph3).
template<bool S1, bool S2, bool S3, bool S4, int VMN>
__device__ __forceinline__ void tile_body(
    int kt, int buf,
    const unsigned short* __restrict__ gA, const unsigned short* __restrict__ gB,
    unsigned short* sA, unsigned short* sB, f32x4 (&acc)[8][4],
    int w, int wr, int wc, int l15, int lg, int r3, int c8s) {
  const unsigned short* pA = sA + buf * 16384;
  const unsigned short* pB = sB + buf * 16384;
  const int l7 = l15 & 7;
  s16x8 fa[4][2], fb[4][2];
  // ---- ph1: ds_read A m0-3 + B all; stage A-h1(kt+1)
#pragma unroll
  for (int m = 0; m < 4; ++m)
#pragma unroll
    for (int ks = 0; ks < 2; ++ks)
      fa[m][ks] = *(const s16x8*)(pA + ((wr * 128 + m * 16 + l15) << 6) + (((ks * 4 + lg) ^ l7) << 3));
#pragma unroll
  for (int n = 0; n < 4; ++n)
#pragma unroll
    for (int ks = 0; ks < 2; ++ks)
      fb[n][ks] = *(const s16x8*)(pB + ((wc * 64 + n * 16 + l15) << 6) + (((ks * 4 + lg) ^ l7) << 3));
  if (S1) stage_half(gA + (128 << 10), (kt + 1) * 64, sA + (buf ^ 1) * 16384 + 8192, w, r3, c8s);
  BAR(); LGKM0(); __builtin_amdgcn_sched_barrier(0);
  __builtin_amdgcn_s_setprio(1);
  MFMA_Q(0, 0);
  __builtin_amdgcn_s_setprio(0);
  BAR();
  // ---- ph2: stage B-h0(kt+2)
  if (S2) stage_half(gB, (kt + 2) * 64, sB + buf * 16384, w, r3, c8s);
  BAR();
  __builtin_amdgcn_s_setprio(1);
  MFMA_Q(0, 2);
  __builtin_amdgcn_s_setprio(0);
  BAR();
  // ---- ph3: ds_read A m4-7; stage B-h1(kt+2)
#pragma unroll
  for (int m = 0; m < 4; ++m)
#pragma unroll
    for (int ks = 0; ks < 2; ++ks)
      fa[m][ks] = *(const s16x8*)(pA + ((wr * 128 + (4 + m) * 16 + l15) << 6) + (((ks * 4 + lg) ^ l7) << 3));
  if (S3) stage_half(gB + (128 << 10), (kt + 2) * 64, sB + buf * 16384 + 8192, w, r3, c8s);
  BAR(); LGKM0(); __builtin_amdgcn_sched_barrier(0);
  __builtin_amdgcn_s_setprio(1);
  MFMA_Q(4, 0);
  __builtin_amdgcn_s_setprio(0);
  BAR();
  // ---- ph4: stage A-h0(kt+2); counted vmcnt checkpoint (tile kt+1 landed)
  if (S4) stage_half(gA, (kt + 2) * 64, sA + buf * 16384, w, r3, c8s);
  if constexpr (VMN == 6) { VMC(6); }
  else if constexpr (VMN == 0) { VMC(0); }
  BAR();
  __builtin_amdgcn_s_setprio(1);
  MFMA_Q(4, 2);
  __builtin_amdgcn_s_setprio(0);
  BAR();
}

// 256x256 tile, 8-phase, double-buffered. score_part[ntile<4][65536 rows].
__global__ __launch_bounds__(512, 2) void k_score_gemm8(
    const unsigned short* __restrict__ vbf, const unsigned short* __restrict__ W2t,
    const float* __restrict__ add2, const float* __restrict__ Vk,
    float* __restrict__ score_part) {
  __shared__ unsigned short sA[32768];   // 2 bufs x 256 rows x 64 k
  __shared__ unsigned short sB[32768];
  const int tid = threadIdx.x;
  const int w = tid >> 6, lane = tid & 63;
  const int wr = w >> 2, wc = w & 3;             // 2 x 4 wave grid
  const int l15 = lane & 15, lg = lane >> 4;
  const int r3 = lane >> 3, c8s = (lane & 7) ^ r3;

  // XCD-contiguous: each XCD walks (mtile, all 4 ntiles) so A-strip is L2-reused.
  const int L = blockIdx.x;
  const int g = (L & 7) * 128 + (L >> 3);
  const int mtile = g >> 2, ntile = g & 3;

  const unsigned short* gA = vbf + ((size_t)mtile << 18);
  const unsigned short* gB = W2t + ((size_t)ntile << 18);

  f32x4 acc[8][4] = {};

  // Prologue: tile0 (all 4 halves) + tile1 (B0,B1,A0); wait tile0 (vmcnt 6).
  stage_half(gA, 0, sA, w, r3, c8s);
  stage_half(gA + (128 << 10), 0, sA + 8192, w, r3, c8s);
  stage_half(gB, 0, sB, w, r3, c8s);
  stage_half(gB + (128 << 10), 0, sB + 8192, w, r3, c8s);
  stage_half(gB, 64, sB + 16384, w, r3, c8s);
  stage_half(gB + (128 << 10), 64, sB + 16384 + 8192, w, r3, c8s);
  stage_half(gA, 64, sA + 16384, w, r3, c8s);
  VMC(6);
  BAR();

  int buf = 0;
  for (int kt = 0; kt < 14; ++kt) {
    tile_body<true, true, true, true, 6>(kt, buf, gA, gB, sA, sB, acc, w, wr, wc, l15, lg, r3, c8s);
    buf ^= 1;
  }
  tile_body<true, false, false, false, 0>(14, buf, gA, gB, sA, sB, acc, w, wr, wc, l15, lg, r3, c8s);
  buf ^= 1;
  tile_body<false, false, false, false, -1>(15, buf, gA, gB, sA, sB, acc, w, wr, wc, l15, lg, r3, c8s);

  // Epilogue: x = acc + add2[b][u]; partial row-sum of tanh(x)*Vk[u] over this 256-col slab
  const int b = (mtile * 256) >> 11;   // block-uniform (256 | 2048)
  float vks[4], adds[4];
#pragma unroll
  for (int n = 0; n < 4; ++n) {
    int u = ntile * 256 + wc * 64 + n * 16 + l15;
    vks[n] = Vk[u];
    adds[n] = add2[(b << 10) + u];
  }
  __syncthreads();
  float* part = (float*)sA;   // [4][256]
#pragma unroll
  for (int m = 0; m < 8; ++m) {
#pragma unroll
    for (int j = 0; j < 4; ++j) {
      float s = 0.f;
#pragma unroll
      for (int n = 0; n < 4; ++n) {
        float x = acc[m][n][j] + adds[n];
        s = fmaf(tanh_fast(x), vks[n], s);
      }
#pragma unroll
      for (int off = 1; off < 16; off <<= 1) s += __shfl_xor(s, off);
      if (l15 == 0) part[wc * 256 + wr * 128 + m * 16 + lg * 4 + j] = s;
    }
  }
  __syncthreads();
  if (tid < 256) {
    float v = part[tid] + part[256 + tid] + part[512 + tid] + part[768 + tid];
    score_part[((size_t)ntile << 16) + mtile * 256 + tid] = v;
  }
}

// add2[b][u] = query[b]·W1_k[:,u] + W1_b[u] + W2_b[u]
__global__ void k_qproj(const float* __restrict__ q, const float* __restrict__ W1,
                        const float* __restrict__ W1b, const float* __restrict__ W2b,
                        float* __restrict__ add2) {
  int u = blockIdx.x * 256 + threadIdx.x;
  int b = blockIdx.y;
  const float* qr = q + (b << 10);
  float s = 0.f;
#pragma unroll 8
  for (int d = 0; d < ND; ++d) s = fmaf(qr[d], W1[d * NU + u], s);
  add2[(b << 10) + u] = s + W1b[u] + W2b[u];
}

// W2_k [D][U] f32 -> W2t [U][D] bf16
__global__ void k_w2t(const float* __restrict__ W2, unsigned short* __restrict__ W2t) {
  __shared__ unsigned short tile[64][65];
  int bu = blockIdx.x * 64, bd = blockIdx.y * 64;
  int x = threadIdx.x & 63, y4 = threadIdx.x >> 6;
#pragma unroll
  for (int r = 0; r < 16; ++r) {
    int dl = y4 * 16 + r;
    tile[x][dl] = f2bf(W2[(size_t)(bd + dl) * NU + bu + x]);
  }
  __syncthreads();
#pragma unroll
  for (int r = 0; r < 16; ++r) {
    int ul = y4 * 16 + r;
    W2t[(size_t)(bu + ul) * ND + bd + x] = tile[ul][x];
  }
}

// values f32 -> bf16
__global__ void k_cvt_values(const float4* __restrict__ v, ushort4* __restrict__ o) {
  const int n4 = NM * ND / 4;
  for (int i = blockIdx.x * blockDim.x + threadIdx.x; i < n4; i += gridDim.x * blockDim.x) {
    float4 f = v[i];
    ushort4 h;
    h.x = f2bf(f.x); h.y = f2bf(f.y); h.z = f2bf(f.z); h.w = f2bf(f.w);
    o[i] = h;
  }
}

// ---- Fallback (small ws): R2's 128^2 reg-staged fused GEMM (8 partials) ----
__global__ __launch_bounds__(256) void k_score_gemm_small(
    const float* __restrict__ values, const unsigned short* __restrict__ W2t,
    const float* __restrict__ add2, const float* __restrict__ Vk,
    float* __restrict__ score_part) {
  __shared__ unsigned short sA[128 * 64];
  __shared__ unsigned short sB[128 * 64];
  const int tid = threadIdx.x;
  const int w = tid >> 6, lane = tid & 63;
  const int wr = w >> 1, wc = w & 1;
  const int l15 = lane & 15, lg = lane >> 4;
  const int r8 = lane >> 3, c8 = lane & 7;
  const int cs8 = c8 ^ r8;
  const int L = blockIdx.x;
  const int mtile = (L & 7) * 64 + ((L >> 3) >> 3);
  const int ntile = (L >> 3) & 7;
  f32x4 acc[4][4] = {};
  for (int kk = 0; kk < 16; ++kk) {
    const int k0 = kk * 64;
#pragma unroll
    for (int i = 0; i < 4; ++i) {
      int nl = (w * 4 + i) * 8 + r8;
      gload_lds16(W2t + ((size_t)(ntile * 128 + nl) << 10) + k0 + cs8 * 8, sB + (w * 4 + i) * 512);
    }
#pragma unroll
    for (int i = 0; i < 8; ++i) {
      int idx = tid + (i << 8);
      int row = idx >> 4, kc = idx & 15;
      const float4 f = *(const float4*)(values + ((size_t)(mtile * 128 + row) << 10) + k0 + kc * 4);
      ushort4 h;
      h.x = f2bf(f.x); h.y = f2bf(f.y); h.z = f2bf(f.z); h.w = f2bf(f.w);
      int cc = (kc >> 1) ^ (row & 7);
      *(ushort4*)(sA + (row << 6) + cc * 8 + (kc & 1) * 4) = h;
    }
    __syncthreads();
#pragma unroll
    for (int ks = 0; ks < 2; ++ks) {
      s16x8 af[4], bfr[4];
#pragma unroll
      for (int m = 0; m < 4; ++m) {
        int row = wr * 64 + m * 16 + l15;
        int cc = (ks * 4 + lg) ^ (l15 & 7);
        af[m] = *(const s16x8*)(sA + (row << 6) + cc * 8);
      }
#pragma unroll
      for (int n = 0; n < 4; ++n) {
        int row = wc * 64 + n * 16 + l15;
        int cc = (ks * 4 + lg) ^ (l15 & 7);
        bfr[n] = *(const s16x8*)(sB + (row << 6) + cc * 8);
      }
#pragma unroll
      for (int m = 0; m < 4; ++m)
#pragma unroll
        for (int n = 0; n < 4; ++n)
          acc[m][n] = __builtin_amdgcn_mfma_f32_16x16x32_bf16(af[m], bfr[n], acc[m][n], 0, 0, 0);
    }
    __syncthreads();
  }
  const int b = (mtile * 128) >> 11;
  float vks[4], adds[4];
#pragma unroll
  for (int n = 0; n < 4; ++n) {
    int u = ntile * 128 + wc * 64 + n * 16 + l15;
    vks[n] = Vk[u];
    adds[n] = add2[(b << 10) + u];
  }
  float rs[4][4];
#pragma unroll
  for (int m = 0; m < 4; ++m)
#pragma unroll
    for (int j = 0; j < 4; ++j) {
      float s = 0.f;
#pragma unroll
      for (int n = 0; n < 4; ++n) {
        float x = acc[m][n][j] + adds[n];
        s = fmaf(tanh_fast(x), vks[n], s);
      }
#pragma unroll
      for (int off = 1; off < 16; off <<= 1) s += __shfl_xor(s, off);
      rs[m][j] = s;
    }
  __syncthreads();
  float* rowsum = (float*)sA;
  if (wc == 0 && l15 == 0)
#pragma unroll
    for (int m = 0; m < 4; ++m)
#pragma unroll
      for (int j = 0; j < 4; ++j) rowsum[wr * 64 + m * 16 + lg * 4 + j] = rs[m][j];
  __syncthreads();
  if (wc == 1 && l15 == 0)
#pragma unroll
    for (int m = 0; m < 4; ++m)
#pragma unroll
      for (int j = 0; j < 4; ++j) rowsum[wr * 64 + m * 16 + lg * 4 + j] += rs[m][j];
  __syncthreads();
  if (tid < 128)
    score_part[((size_t)ntile << 16) + mtile * 128 + tid] = rowsum[tid];
}

// softmax over T per batch; sums npart N-tile partials first (deterministic)
__global__ void k_softmax(const float* __restrict__ sp, float* __restrict__ w, int npart) {
  __shared__ float redm[4], reds[4];
  int b = blockIdx.x, tid = threadIdx.x;
  float s[8];
  float mx = -1e30f;
#pragma unroll
  for (int i = 0; i < 8; ++i) {
    int t = i * 256 + tid;
    float v = 0.f;
    for (int p = 0; p < npart; ++p) v += sp[((size_t)p << 16) + (b << 11) + t];
    s[i] = v;
    mx = fmaxf(mx, v);
  }
#pragma unroll
  for (int o = 1; o < 64; o <<= 1) mx = fmaxf(mx, __shfl_xor(mx, o));
  if ((tid & 63) == 0) redm[tid >> 6] = mx;
  __syncthreads();
  mx = fmaxf(fmaxf(redm[0], redm[1]), fmaxf(redm[2], redm[3]));
  float sum = 0.f;
#pragma unroll
  for (int i = 0; i < 8; ++i) { s[i] = __expf(s[i] - mx); sum += s[i]; }
#pragma unroll
  for (int o = 1; o < 64; o <<= 1) sum += __shfl_xor(sum, o);
  if ((tid & 63) == 0) reds[tid >> 6] = sum;
  __syncthreads();
  float inv = 1.0f / (reds[0] + reds[1] + reds[2] + reds[3]);
#pragma unroll
  for (int i = 0; i < 8; ++i) w[(b << 11) + i * 256 + tid] = s[i] * inv;
}

// context partials: part[tc][b][d] = sum_{t in chunk} w[b][t]*values[b][t][d]
__global__ void k_context(const float* __restrict__ values, const float* __restrict__ wv,
                          float* __restrict__ part) {
  int d = blockIdx.x * 256 + threadIdx.x;
  int b = blockIdx.y, tc = blockIdx.z;
  const float* vb = values + ((size_t)b << 21) + ((size_t)tc << 18) + d;
  const float* wb = wv + (b << 11) + (tc << 8);
  float acc = 0.f;
#pragma unroll 8
  for (int t = 0; t < 256; ++t) acc = fmaf(wb[t], vb[(size_t)t << 10], acc);
  part[(((size_t)tc * NB + b) << 10) + d] = acc;
}

__global__ void k_ctx_reduce(const float* __restrict__ part, float* __restrict__ out) {
  int i = blockIdx.x * 256 + threadIdx.x;  // 32768
  float s = 0.f;
#pragma unroll
  for (int p = 0; p < 8; ++p) s += part[(p << 15) + i];
  out[i] = s;
}

extern "C" void kernel_launch(void* const* d_in, const int* in_sizes, int n_in,
                              void* d_out, int out_size, void* d_ws, size_t ws_size,
                              hipStream_t stream) {
  const float* query  = (const float*)d_in[0];
  const float* values = (const float*)d_in[1];
  const float* W1k    = (const float*)d_in[2];
  const float* W1b    = (const float*)d_in[3];
  const float* W2k    = (const float*)d_in[4];
  const float* W2b    = (const float*)d_in[5];
  const float* Vk     = (const float*)d_in[6];
  // V_b dropped: softmax is shift-invariant.
  float* out = (float*)d_out;
  char* ws = (char*)d_ws;

  size_t off = 0;
  float* add2 = (float*)(ws + off); off += (size_t)NB * NU * 4;
  float* sp   = (float*)(ws + off); off += (size_t)8 * NM * 4;
  float* wv   = (float*)(ws + off); off += (size_t)NM * 4;
  float* ctxp = (float*)(ws + off); off += (size_t)8 * NB * ND * 4;
  unsigned short* W2t = (unsigned short*)(ws + off); off += (size_t)NU * ND * 2;
  unsigned short* vbf = (unsigned short*)(ws + off);
  size_t need_big = off + (size_t)NM * ND * 2;
  bool big = ws_size >= need_big;

  k_qproj<<<dim3(4, 32), 256, 0, stream>>>(query, W1k, W1b, W2b, add2);
  k_w2t<<<dim3(16, 16), 256, 0, stream>>>(W2k, W2t);
  if (big) {
    k_cvt_values<<<dim3(2048), 256, 0, stream>>>((const float4*)values, (ushort4*)vbf);
    k_score_gemm8<<<dim3(1024), 512, 0, stream>>>(vbf, W2t, add2, Vk, sp);
    k_softmax<<<dim3(32), 256, 0, stream>>>(sp, wv, 4);
  } else {
    k_score_gemm_small<<<dim3(4096), 256, 0, stream>>>(values, W2t, add2, Vk, sp);
    k_softmax<<<dim3(32), 256, 0, stream>>>(sp, wv, 8);
  }
  k_context<<<dim3(4, 32, 8), 256, 0, stream>>>(values, wv, ctxp);
  k_ctx_reduce<<<dim3(128), 256, 0, stream>>>(ctxp, out);
}

// Round 4
// 323.203 us; speedup vs baseline: 1.2806x; 1.1119x over previous
//
#include <hip/hip_runtime.h>

#define NB 32
#define NT 2048
#define ND 1024
#define NU 1024
#define NM (NB*NT)   // 65536 rows

using f32x4 = __attribute__((ext_vector_type(4))) float;
using s16x8 = __attribute__((ext_vector_type(8))) short;

#define BAR()   asm volatile("s_barrier" ::: "memory")
#define LGKM0() asm volatile("s_waitcnt lgkmcnt(0)" ::: "memory")
#define VMC(n)  asm volatile("s_waitcnt vmcnt(" #n ")" ::: "memory")

__device__ __forceinline__ unsigned short f2bf(float f) {
  unsigned u = __builtin_bit_cast(unsigned, f);
  u = u + 0x7fffu + ((u >> 16) & 1u);   // round-to-nearest-even
  return (unsigned short)(u >> 16);
}

__device__ __forceinline__ unsigned cvtpk(float lo, float hi) {
  unsigned r;
  asm("v_cvt_pk_bf16_f32 %0, %1, %2" : "=v"(r) : "v"(lo), "v"(hi));
  return r;
}

__device__ __forceinline__ void gload_lds16(const void* g, void* l) {
  __builtin_amdgcn_global_load_lds(
      (const __attribute__((address_space(1))) unsigned int*)g,
      (__attribute__((address_space(3))) unsigned int*)l, 16, 0, 0);
}

__device__ __forceinline__ float tanh_fast(float x) {
  float e = __expf(2.0f * x);
  return 1.0f - 2.0f * __builtin_amdgcn_rcpf(e + 1.0f);
}

// B half-tile (128 rows x 64 k bf16 = 16KB) via global_load_lds; source chunk
// pre-XOR-swizzled (m173), LDS dest linear.
__device__ __forceinline__ void stage_half(const unsigned short* g, int gk,
                                           unsigned short* l, int w, int r3, int c8s) {
#pragma unroll
  for (int i = 0; i < 2; ++i) {
    int cb = i * 8 + w;
    gload_lds16(g + (((size_t)(cb * 8 + r3)) << 10) + gk + c8s * 8, l + cb * 512);
  }
}

// A staging: thread covers row=tid>>2 (h0) / 128+(tid>>2) (h1), k-slice (tid&3)*16..+15
__device__ __forceinline__ void load_halfA(const float* g, int kbase, int arow, int acol,
                                           float4 (&f)[4]) {
  const float* p = g + ((size_t)arow << 10) + kbase + acol * 16;
  f[0] = *(const float4*)(p);
  f[1] = *(const float4*)(p + 4);
  f[2] = *(const float4*)(p + 8);
  f[3] = *(const float4*)(p + 12);
}

__device__ __forceinline__ void cvt_half(const float4 (&f)[4], unsigned (&pk)[8]) {
  pk[0] = cvtpk(f[0].x, f[0].y); pk[1] = cvtpk(f[0].z, f[0].w);
  pk[2] = cvtpk(f[1].x, f[1].y); pk[3] = cvtpk(f[1].z, f[1].w);
  pk[4] = cvtpk(f[2].x, f[2].y); pk[5] = cvtpk(f[2].z, f[2].w);
  pk[6] = cvtpk(f[3].x, f[3].y); pk[7] = cvtpk(f[3].z, f[3].w);
}

__device__ __forceinline__ void write_half(const unsigned (&pk)[8], unsigned short* lds,
                                           int row, int acol) {
  int r7 = row & 7;
  int c0 = (acol * 2) ^ r7, c1 = (acol * 2 + 1) ^ r7;
  *(uint4*)(lds + (row << 6) + c0 * 8) = make_uint4(pk[0], pk[1], pk[2], pk[3]);
  *(uint4*)(lds + (row << 6) + c1 * 8) = make_uint4(pk[4], pk[5], pk[6], pk[7]);
}

#define MFMA_Q(MB, NBASE) \
  _Pragma("unroll") \
  for (int m = 0; m < 4; ++m) { \
    _Pragma("unroll") \
    for (int n = 0; n < 2; ++n) { \
      _Pragma("unroll") \
      for (int ks = 0; ks < 2; ++ks) \
        acc[(MB) + m][(NBASE) + n] = __builtin_amdgcn_mfma_f32_16x16x32_bf16( \
            fa[m][ks], fb[n][ks], acc[(MB) + m][(NBASE) + n], 0, 0, 0); \
    } \
  }

// One K-tile, 4 phases, quadrant order Q00,Q02,Q42,Q40 (fb23 reused ph2-ph3).
// A(kt+2) f32: h0 issued ph1, cvt'd ph3; h1 issued ph3, cvt'd ph4; written ph3/ph4
// into CURRENT buf (A(kt) reads complete at ph3). B(kt+1) staged ph2/ph3 into buf^1.
template<bool AISS, bool BST>
__device__ __forceinline__ void tile_body(
    int kt, int buf, const float* gA, const unsigned short* gB,
    unsigned short* sA, unsigned short* sB, f32x4 (&acc)[8][4],
    int w, int wr, int wc, int l15, int lg, int r3, int c8s, int arow, int acol) {
  const unsigned short* pA = sA + buf * 16384;
  const unsigned short* pB = sB + buf * 16384;
  unsigned short* nA = sA + buf * 16384;          // A(kt+2) dest (same buf)
  unsigned short* nB = sB + (buf ^ 1) * 16384;    // B(kt+1) dest
  const int l7 = l15 & 7;
  s16x8 fa[4][2], fb[2][2];
  float4 ah[4];
  unsigned pk0[8], pk1[8];
  // ---------- ph1: fa0-3 + fb0-1; issue A-h0(kt+2)
  VMC(0);
#pragma unroll
  for (int m = 0; m < 4; ++m)
#pragma unroll
    for (int ks = 0; ks < 2; ++ks)
      fa[m][ks] = *(const s16x8*)(pA + ((wr * 128 + m * 16 + l15) << 6) + (((ks * 4 + lg) ^ l7) << 3));
#pragma unroll
  for (int n = 0; n < 2; ++n)
#pragma unroll
    for (int ks = 0; ks < 2; ++ks)
      fb[n][ks] = *(const s16x8*)(pB + ((wc * 64 + n * 16 + l15) << 6) + (((ks * 4 + lg) ^ l7) << 3));
  if (AISS) load_halfA(gA, (kt + 2) * 64, arow, acol, ah);
  BAR(); LGKM0(); __builtin_amdgcn_sched_barrier(0);
  __builtin_amdgcn_s_setprio(1); MFMA_Q(0, 0); __builtin_amdgcn_s_setprio(0);
  BAR();
  // ---------- ph2: fb2-3; stage B-h0(kt+1)
#pragma unroll
  for (int n = 0; n < 2; ++n)
#pragma unroll
    for (int ks = 0; ks < 2; ++ks)
      fb[n][ks] = *(const s16x8*)(pB + ((wc * 64 + (2 + n) * 16 + l15) << 6) + (((ks * 4 + lg) ^ l7) << 3));
  if (BST) stage_half(gB, (kt + 1) * 64, nB, w, r3, c8s);
  BAR(); LGKM0(); __builtin_amdgcn_sched_barrier(0);
  __builtin_amdgcn_s_setprio(1); MFMA_Q(0, 2); __builtin_amdgcn_s_setprio(0);
  BAR();
  // ---------- ph3: fa4-7 (reuse fb2-3); cvt A-h0, write; issue A-h1; stage B-h1
#pragma unroll
  for (int m = 0; m < 4; ++m)
#pragma unroll
    for (int ks = 0; ks < 2; ++ks)
      fa[m][ks] = *(const s16x8*)(pA + ((wr * 128 + (4 + m) * 16 + l15) << 6) + (((ks * 4 + lg) ^ l7) << 3));
  if (AISS) {
    VMC(2);                       // drain A-h0 (4); leave B-h0 gloads (2)
    cvt_half(ah, pk0);
    load_halfA(gA + (128 << 10), (kt + 2) * 64, arow, acol, ah);
  }
  if (BST) stage_half(gB + (128 << 10), (kt + 1) * 64, nB + 8192, w, r3, c8s);
  BAR(); LGKM0(); __builtin_amdgcn_sched_barrier(0);
  __builtin_amdgcn_s_setprio(1); MFMA_Q(4, 2); __builtin_amdgcn_s_setprio(0);
  // write h0 after MFMA (A(kt) reads fully drained at this phase's LGKM0+BAR... h0 rows
  // 0-127 were last read at ph3's fa when wr==0 -> writes must come after the barrier:
  BAR();
  // ---------- ph4: re-read fb0-1; cvt A-h1; write both halves
#pragma unroll
  for (int n = 0; n < 2; ++n)
#pragma unroll
    for (int ks = 0; ks < 2; ++ks)
      fb[n][ks] = *(const s16x8*)(pB + ((wc * 64 + n * 16 + l15) << 6) + (((ks * 4 + lg) ^ l7) << 3));
  if (AISS) {
    VMC(2);                       // drain A-h1 (4); leave B-h1 gloads (2)
    cvt_half(ah, pk1);
  }
  LGKM0(); __builtin_amdgcn_sched_barrier(0);
  __builtin_amdgcn_s_setprio(1); MFMA_Q(4, 0); __builtin_amdgcn_s_setprio(0);
  if (AISS) {
    write_half(pk0, nA, arow, acol);
    write_half(pk1, nA, 128 + arow, acol);
  }
  BAR();
}

// 256x256 tile, 8-phase, dbuf, A reg-staged f32->bf16. score_part[4][65536].
__global__ __launch_bounds__(512, 2) void k_score_gemm8(
    const float* __restrict__ values, const unsigned short* __restrict__ W2t,
    const float* __restrict__ add2, const float* __restrict__ Vk,
    float* __restrict__ score_part) {
  __shared__ unsigned short sA[32768];
  __shared__ unsigned short sB[32768];
  const int tid = threadIdx.x;
  const int w = tid >> 6, lane = tid & 63;
  const int wr = w >> 2, wc = w & 3;
  const int l15 = lane & 15, lg = lane >> 4;
  const int r3 = lane >> 3, c8s = (lane & 7) ^ r3;
  const int arow = tid >> 2, acol = tid & 3;

  const int L = blockIdx.x;
  const int g = (L & 7) * 128 + (L >> 3);
  const int mtile = g >> 2, ntile = g & 3;

  const float* gA = values + ((size_t)mtile << 18);
  const unsigned short* gB = W2t + ((size_t)ntile << 18);

  f32x4 acc[8][4] = {};

  // Prologue: A(0)->buf0, A(1)->buf1 (reg-staged), B(0)->buf0 (gload).
  {
    float4 f0[4], f1[4];
    unsigned p0[8], p1[8];
    load_halfA(gA, 0, arow, acol, f0);
    load_halfA(gA + (128 << 10), 0, arow, acol, f1);
    VMC(0);
    cvt_half(f0, p0); cvt_half(f1, p1);
    write_half(p0, sA, arow, acol);
    write_half(p1, sA, 128 + arow, acol);
    load_halfA(gA, 64, arow, acol, f0);
    load_halfA(gA + (128 << 10), 64, arow, acol, f1);
    stage_half(gB, 0, sB, w, r3, c8s);
    stage_half(gB + (128 << 10), 0, sB + 8192, w, r3, c8s);
    VMC(4);   // drain A(1) 8 loads; leave B(0) 4 gloads
    cvt_half(f0, p0); cvt_half(f1, p1);
    write_half(p0, sA + 16384, arow, acol);
    write_half(p1, sA + 16384, 128 + arow, acol);
    VMC(0);   // B(0) landed
    LGKM0();
    BAR();
  }

  int buf = 0;
  for (int kt = 0; kt < 14; ++kt) {
    tile_body<true, true>(kt, buf, gA, gB, sA, sB, acc, w, wr, wc, l15, lg, r3, c8s, arow, acol);
    buf ^= 1;
  }
  tile_body<false, true>(14, buf, gA, gB, sA, sB, acc, w, wr, wc, l15, lg, r3, c8s, arow, acol);
  buf ^= 1;
  tile_body<false, false>(15, buf, gA, gB, sA, sB, acc, w, wr, wc, l15, lg, r3, c8s, arow, acol);

  // Epilogue: x = acc + add2[b][u]; row-sum of tanh(x)*Vk[u] over this 256-col slab
  const int b = (mtile * 256) >> 11;
  float vks[4], adds[4];
#pragma unroll
  for (int n = 0; n < 4; ++n) {
    int u = ntile * 256 + wc * 64 + n * 16 + l15;
    vks[n] = Vk[u];
    adds[n] = add2[(b << 10) + u];
  }
  __syncthreads();
  float* part = (float*)sA;   // [4][256]
#pragma unroll
  for (int m = 0; m < 8; ++m) {
#pragma unroll
    for (int j = 0; j < 4; ++j) {
      float s = 0.f;
#pragma unroll
      for (int n = 0; n < 4; ++n) {
        float x = acc[m][n][j] + adds[n];
        s = fmaf(tanh_fast(x), vks[n], s);
      }
#pragma unroll
      for (int off = 1; off < 16; off <<= 1) s += __shfl_xor(s, off);
      if (l15 == 0) part[wc * 256 + wr * 128 + m * 16 + lg * 4 + j] = s;
    }
  }
  __syncthreads();
  if (tid < 256) {
    float v = part[tid] + part[256 + tid] + part[512 + tid] + part[768 + tid];
    score_part[((size_t)ntile << 16) + mtile * 256 + tid] = v;
  }
}

// add2[b][u] = query[b]·W1_k[:,u] + W1_b[u] + W2_b[u]
__global__ void k_qproj(const float* __restrict__ q, const float* __restrict__ W1,
                        const float* __restrict__ W1b, const float* __restrict__ W2b,
                        float* __restrict__ add2) {
  int u = blockIdx.x * 256 + threadIdx.x;
  int b = blockIdx.y;
  const float* qr = q + (b << 10);
  float s = 0.f;
#pragma unroll 8
  for (int d = 0; d < ND; ++d) s = fmaf(qr[d], W1[d * NU + u], s);
  add2[(b << 10) + u] = s + W1b[u] + W2b[u];
}

// W2_k [D][U] f32 -> W2t [U][D] bf16
__global__ void k_w2t(const float* __restrict__ W2, unsigned short* __restrict__ W2t) {
  __shared__ unsigned short tile[64][65];
  int bu = blockIdx.x * 64, bd = blockIdx.y * 64;
  int x = threadIdx.x & 63, y4 = threadIdx.x >> 6;
#pragma unroll
  for (int r = 0; r < 16; ++r) {
    int dl = y4 * 16 + r;
    tile[x][dl] = f2bf(W2[(size_t)(bd + dl) * NU + bu + x]);
  }
  __syncthreads();
#pragma unroll
  for (int r = 0; r < 16; ++r) {
    int ul = y4 * 16 + r;
    W2t[(size_t)(bu + ul) * ND + bd + x] = tile[ul][x];
  }
}

// softmax over T per batch; sums 4 N-tile partials first (deterministic)
__global__ void k_softmax(const float* __restrict__ sp, float* __restrict__ w) {
  __shared__ float redm[4], reds[4];
  int b = blockIdx.x, tid = threadIdx.x;
  float s[8];
  float mx = -1e30f;
#pragma unroll
  for (int i = 0; i < 8; ++i) {
    int t = i * 256 + tid;
    float v = 0.f;
#pragma unroll
    for (int p = 0; p < 4; ++p) v += sp[((size_t)p << 16) + (b << 11) + t];
    s[i] = v;
    mx = fmaxf(mx, v);
  }
#pragma unroll
  for (int o = 1; o < 64; o <<= 1) mx = fmaxf(mx, __shfl_xor(mx, o));
  if ((tid & 63) == 0) redm[tid >> 6] = mx;
  __syncthreads();
  mx = fmaxf(fmaxf(redm[0], redm[1]), fmaxf(redm[2], redm[3]));
  float sum = 0.f;
#pragma unroll
  for (int i = 0; i < 8; ++i) { s[i] = __expf(s[i] - mx); sum += s[i]; }
#pragma unroll
  for (int o = 1; o < 64; o <<= 1) sum += __shfl_xor(sum, o);
  if ((tid & 63) == 0) reds[tid >> 6] = sum;
  __syncthreads();
  float inv = 1.0f / (reds[0] + reds[1] + reds[2] + reds[3]);
#pragma unroll
  for (int i = 0; i < 8; ++i) w[(b << 11) + i * 256 + tid] = s[i] * inv;
}

// context partials: part[tc][b][d] = sum_{t in chunk} w[b][t]*values[b][t][d] (float4)
__global__ void k_context(const float* __restrict__ values, const float* __restrict__ wv,
                          float* __restrict__ part) {
  int d4 = threadIdx.x;                 // 256 threads -> d = d4*4
  int b = blockIdx.y, tc = blockIdx.z;
  const float4* vb = (const float4*)(values + ((size_t)b << 21) + ((size_t)tc << 18)) + d4;
  const float* wb = wv + (b << 11) + (tc << 8);
  float ax = 0.f, ay = 0.f, az = 0.f, aw = 0.f;
#pragma unroll 4
  for (int t = 0; t < 256; ++t) {
    float4 v = vb[(size_t)t << 8];
    float wt = wb[t];
    ax = fmaf(wt, v.x, ax); ay = fmaf(wt, v.y, ay);
    az = fmaf(wt, v.z, az); aw = fmaf(wt, v.w, aw);
  }
  float4* po = (float4*)(part + (((size_t)tc * NB + b) << 10)) + d4;
  *po = make_float4(ax, ay, az, aw);
}

__global__ void k_ctx_reduce(const float* __restrict__ part, float* __restrict__ out) {
  int i = blockIdx.x * 256 + threadIdx.x;  // 32768
  float s = 0.f;
#pragma unroll
  for (int p = 0; p < 8; ++p) s += part[(p << 15) + i];
  out[i] = s;
}

extern "C" void kernel_launch(void* const* d_in, const int* in_sizes, int n_in,
                              void* d_out, int out_size, void* d_ws, size_t ws_size,
                              hipStream_t stream) {
  const float* query  = (const float*)d_in[0];
  const float* values = (const float*)d_in[1];
  const float* W1k    = (const float*)d_in[2];
  const float* W1b    = (const float*)d_in[3];
  const float* W2k    = (const float*)d_in[4];
  const float* W2b    = (const float*)d_in[5];
  const float* Vk     = (const float*)d_in[6];
  // V_b dropped: softmax is shift-invariant.
  float* out = (float*)d_out;
  char* ws = (char*)d_ws;

  size_t off = 0;
  float* add2 = (float*)(ws + off); off += (size_t)NB * NU * 4;          // 128 KB
  float* sp   = (float*)(ws + off); off += (size_t)4 * NM * 4;           // 1 MB
  float* wv   = (float*)(ws + off); off += (size_t)NM * 4;               // 256 KB
  float* ctxp = (float*)(ws + off); off += (size_t)8 * NB * ND * 4;      // 1 MB
  unsigned short* W2t = (unsigned short*)(ws + off); off += (size_t)NU * ND * 2; // 2 MB

  k_qproj<<<dim3(4, 32), 256, 0, stream>>>(query, W1k, W1b, W2b, add2);
  k_w2t<<<dim3(16, 16), 256, 0, stream>>>(W2k, W2t);
  k_score_gemm8<<<dim3(1024), 512, 0, stream>>>(values, W2t, add2, Vk, sp);
  k_softmax<<<dim3(32), 256, 0, stream>>>(sp, wv);
  k_context<<<dim3(1, 32, 8), 256, 0, stream>>>(values, wv, ctxp);
  k_ctx_reduce<<<dim3(128), 256, 0, stream>>>(ctxp, out);
}

// Round 5
// 298.227 us; speedup vs baseline: 1.3878x; 1.0837x over previous
//
#include <hip/hip_runtime.h>

#define NB 32
#define NT 2048
#define ND 1024
#define NU 1024
#define NM (NB*NT)   // 65536 rows

using f32x4 = __attribute__((ext_vector_type(4))) float;
using s16x8 = __attribute__((ext_vector_type(8))) short;

#define BAR()   asm volatile("s_barrier" ::: "memory")
#define LGKM0() asm volatile("s_waitcnt lgkmcnt(0)" ::: "memory")
#define VMC(n)  asm volatile("s_waitcnt vmcnt(" #n ")" ::: "memory")
#define SB0()   __builtin_amdgcn_sched_barrier(0)

__device__ __forceinline__ unsigned short f2bf(float f) {
  unsigned u = __builtin_bit_cast(unsigned, f);
  u = u + 0x7fffu + ((u >> 16) & 1u);   // round-to-nearest-even
  return (unsigned short)(u >> 16);
}

__device__ __forceinline__ unsigned cvtpk(float lo, float hi) {
  unsigned r;
  asm("v_cvt_pk_bf16_f32 %0, %1, %2" : "=v"(r) : "v"(lo), "v"(hi));
  return r;
}

__device__ __forceinline__ void gload_lds16(const void* g, void* l) {
  __builtin_amdgcn_global_load_lds(
      (const __attribute__((address_space(1))) unsigned int*)g,
      (__attribute__((address_space(3))) unsigned int*)l, 16, 0, 0);
}

__device__ __forceinline__ float tanh_fast(float x) {
  float e = __expf(2.0f * x);
  return 1.0f - 2.0f * __builtin_amdgcn_rcpf(e + 1.0f);
}

// B half-tile (128 rows x 64 k bf16 = 16KB) via global_load_lds; source chunk
// pre-XOR-swizzled (m173), LDS dest linear. All 8 waves, 2 gloads/thread.
__device__ __forceinline__ void stage_half(const unsigned short* g, int gk,
                                           unsigned short* l, int w, int r3, int c8s) {
#pragma unroll
  for (int i = 0; i < 2; ++i) {
    int cb = i * 8 + w;
    gload_lds16(g + (((size_t)(cb * 8 + r3)) << 10) + gk + c8s * 8, l + cb * 512);
  }
}

// A f32 loads: thread covers row arow (h0) / 128+arow (h1), k-slice acol*16..+15
__device__ __forceinline__ void load_halfA(const float* g, int kbase, int arow, int acol,
                                           float4 (&f)[4]) {
  const float* p = g + ((size_t)arow << 10) + kbase + acol * 16;
  f[0] = *(const float4*)(p);
  f[1] = *(const float4*)(p + 4);
  f[2] = *(const float4*)(p + 8);
  f[3] = *(const float4*)(p + 12);
}

__device__ __forceinline__ void cvt_half(const float4 (&f)[4], unsigned (&pk)[8]) {
  pk[0] = cvtpk(f[0].x, f[0].y); pk[1] = cvtpk(f[0].z, f[0].w);
  pk[2] = cvtpk(f[1].x, f[1].y); pk[3] = cvtpk(f[1].z, f[1].w);
  pk[4] = cvtpk(f[2].x, f[2].y); pk[5] = cvtpk(f[2].z, f[2].w);
  pk[6] = cvtpk(f[3].x, f[3].y); pk[7] = cvtpk(f[3].z, f[3].w);
}

__device__ __forceinline__ void write_half(const unsigned (&pk)[8], unsigned short* lds,
                                           int row, int acol) {
  int r7 = row & 7;
  int c0 = (acol * 2) ^ r7, c1 = (acol * 2 + 1) ^ r7;
  *(uint4*)(lds + (row << 6) + c0 * 8) = make_uint4(pk[0], pk[1], pk[2], pk[3]);
  *(uint4*)(lds + (row << 6) + c1 * 8) = make_uint4(pk[4], pk[5], pk[6], pk[7]);
}

#define MFMA_Q(MB, NB2) \
  _Pragma("unroll") \
  for (int m = 0; m < 4; ++m) { \
    _Pragma("unroll") \
    for (int n = 0; n < 2; ++n) { \
      _Pragma("unroll") \
      for (int ks = 0; ks < 2; ++ks) \
        acc[(MB) + m][(NB2) + n] = __builtin_amdgcn_mfma_f32_16x16x32_bf16( \
            fa[m][ks], fb[(NB2) + n][ks], acc[(MB) + m][(NB2) + n], 0, 0, 0); \
    } \
  }

// Tile T pipeline (no manual vmcnt in loop — compiler's reg-dep waits are the
// counted waits; B halves are strictly older than the A half each cvt waits on):
//  ph1: ds_read fa(h0) + fb(all);           MFMA Q(0,0)
//  ph2: cvt+write A(T+1) h0 -> bufA^1; stage B(T+2) h0 -> pB;  MFMA Q(0,2)
//  ph3: ds_read fa(h1); cvt+write A(T+1) h1; issue A(T+2) h0; stage B(T+2) h1; Q(4,0)
//  ph4: issue A(T+2) h1;                    MFMA Q(4,2)
template<bool ACVT, bool AISS, bool BST>
__device__ __forceinline__ void tile_body(
    int kt, int buf, const float* gA, const unsigned short* gB,
    unsigned short* sA, unsigned short* sB, f32x4 (&acc)[8][4], float4 (&ah)[2][4],
    int w, int wr, int wc, int l15, int lg, int r3, int c8s, int arow, int acol) {
  const unsigned short* pA = sA + buf * 16384;
  const unsigned short* pB = sB + buf * 16384;
  unsigned short* wA = sA + (buf ^ 1) * 16384;   // A(kt+1) dest
  unsigned short* nB = sB + buf * 16384;         // B(kt+2) dest (fb all read at ph1)
  const int l7 = l15 & 7;
  s16x8 fa[4][2], fb[4][2];
  // ---------- ph1
#pragma unroll
  for (int m = 0; m < 4; ++m)
#pragma unroll
    for (int ks = 0; ks < 2; ++ks)
      fa[m][ks] = *(const s16x8*)(pA + ((wr * 128 + m * 16 + l15) << 6) + (((ks * 4 + lg) ^ l7) << 3));
#pragma unroll
  for (int n = 0; n < 4; ++n)
#pragma unroll
    for (int ks = 0; ks < 2; ++ks)
      fb[n][ks] = *(const s16x8*)(pB + ((wc * 64 + n * 16 + l15) << 6) + (((ks * 4 + lg) ^ l7) << 3));
  BAR(); LGKM0(); SB0();
  __builtin_amdgcn_s_setprio(1); MFMA_Q(0, 0); __builtin_amdgcn_s_setprio(0);
  BAR();
  // ---------- ph2
  if (ACVT) {
    unsigned pk[8];
    cvt_half(ah[0], pk);                 // compiler-counted vmcnt wait
    write_half(pk, wA, arow, acol);
  }
  if (BST) stage_half(gB, (kt + 2) * 64, nB, w, r3, c8s);
  __builtin_amdgcn_s_setprio(1); MFMA_Q(0, 2); __builtin_amdgcn_s_setprio(0);
  LGKM0();                               // drain ds_writes before barrier
  BAR();
  // ---------- ph3
#pragma unroll
  for (int m = 0; m < 4; ++m)
#pragma unroll
    for (int ks = 0; ks < 2; ++ks)
      fa[m][ks] = *(const s16x8*)(pA + ((wr * 128 + (4 + m) * 16 + l15) << 6) + (((ks * 4 + lg) ^ l7) << 3));
  if (ACVT) {
    unsigned pk[8];
    cvt_half(ah[1], pk);
    write_half(pk, wA, 128 + arow, acol);
  }
  if (AISS) load_halfA(gA, (kt + 2) * 64, arow, acol, ah[0]);
  if (BST) stage_half(gB + (128 << 10), (kt + 2) * 64, nB + 8192, w, r3, c8s);
  LGKM0(); SB0();
  __builtin_amdgcn_s_setprio(1); MFMA_Q(4, 0); __builtin_amdgcn_s_setprio(0);
  BAR();
  // ---------- ph4
  if (AISS) load_halfA(gA + (128 << 10), (kt + 2) * 64, arow, acol, ah[1]);
  __builtin_amdgcn_s_setprio(1); MFMA_Q(4, 2); __builtin_amdgcn_s_setprio(0);
  BAR();
}

// 256x256 tile, 8-phase, dbuf, A reg-staged f32->bf16 deep pipeline.
__global__ __launch_bounds__(512, 2) void k_score_gemm8(
    const float* __restrict__ values, const unsigned short* __restrict__ W2t,
    const float* __restrict__ add2, const float* __restrict__ Vk,
    float* __restrict__ score_part) {
  __shared__ unsigned short sA[32768];   // 2 bufs x 256 x 64
  __shared__ unsigned short sB[32768];
  const int tid = threadIdx.x;
  const int w = tid >> 6, lane = tid & 63;
  const int wr = w >> 2, wc = w & 3;
  const int l15 = lane & 15, lg = lane >> 4;
  const int r3 = lane >> 3, c8s = (lane & 7) ^ r3;
  const int arow = tid >> 2, acol = tid & 3;

  const int L = blockIdx.x;
  const int g = (L & 7) * 128 + (L >> 3);
  const int mtile = g >> 2, ntile = g & 3;

  const float* gA = values + ((size_t)mtile << 18);
  const unsigned short* gB = W2t + ((size_t)ntile << 18);

  f32x4 acc[8][4] = {};
  float4 ah[2][4];

  // Prologue: A(0)->bufA0 (reg cvt), B(0)->bufB0, B(1)->bufB1 (gload), issue A(1).
  {
    float4 f0[4], f1[4];
    unsigned p0[8], p1[8];
    load_halfA(gA, 0, arow, acol, f0);
    load_halfA(gA + (128 << 10), 0, arow, acol, f1);
    cvt_half(f0, p0); cvt_half(f1, p1);
    write_half(p0, sA, arow, acol);
    write_half(p1, sA, 128 + arow, acol);
    stage_half(gB, 0, sB, w, r3, c8s);
    stage_half(gB + (128 << 10), 0, sB + 8192, w, r3, c8s);
    stage_half(gB, 64, sB + 16384, w, r3, c8s);
    stage_half(gB + (128 << 10), 64, sB + 16384 + 8192, w, r3, c8s);
    load_halfA(gA, 64, arow, acol, ah[0]);
    load_halfA(gA + (128 << 10), 64, arow, acol, ah[1]);
    VMC(8);    // B(0),B(1) landed; A(1)'s 8 loads stay in flight
    LGKM0();   // A(0) ds_writes visible
    BAR();
  }

  int buf = 0;
  for (int kt = 0; kt < 14; ++kt) {
    tile_body<true, true, true>(kt, buf, gA, gB, sA, sB, acc, ah, w, wr, wc, l15, lg, r3, c8s, arow, acol);
    buf ^= 1;
  }
  tile_body<true, false, false>(14, buf, gA, gB, sA, sB, acc, ah, w, wr, wc, l15, lg, r3, c8s, arow, acol);
  buf ^= 1;
  tile_body<false, false, false>(15, buf, gA, gB, sA, sB, acc, ah, w, wr, wc, l15, lg, r3, c8s, arow, acol);

  // Epilogue: x = acc + add2[b][u]; row-sum of tanh(x)*Vk[u] over this 256-col slab
  const int b = (mtile * 256) >> 11;
  float vks[4], adds[4];
#pragma unroll
  for (int n = 0; n < 4; ++n) {
    int u = ntile * 256 + wc * 64 + n * 16 + l15;
    vks[n] = Vk[u];
    adds[n] = add2[(b << 10) + u];
  }
  __syncthreads();
  float* part = (float*)sA;   // [4][256]
#pragma unroll
  for (int m = 0; m < 8; ++m) {
#pragma unroll
    for (int j = 0; j < 4; ++j) {
      float s = 0.f;
#pragma unroll
      for (int n = 0; n < 4; ++n) {
        float x = acc[m][n][j] + adds[n];
        s = fmaf(tanh_fast(x), vks[n], s);
      }
#pragma unroll
      for (int off = 1; off < 16; off <<= 1) s += __shfl_xor(s, off);
      if (l15 == 0) part[wc * 256 + wr * 128 + m * 16 + lg * 4 + j] = s;
    }
  }
  __syncthreads();
  if (tid < 256) {
    float v = part[tid] + part[256 + tid] + part[512 + tid] + part[768 + tid];
    score_part[((size_t)ntile << 16) + mtile * 256 + tid] = v;
  }
}

// add2[b][u] = query[b]·W1_k[:,u] + W1_b[u] + W2_b[u]
__global__ void k_qproj(const float* __restrict__ q, const float* __restrict__ W1,
                        const float* __restrict__ W1b, const float* __restrict__ W2b,
                        float* __restrict__ add2) {
  int u = blockIdx.x * 256 + threadIdx.x;
  int b = blockIdx.y;
  const float* qr = q + (b << 10);
  float s = 0.f;
#pragma unroll 8
  for (int d = 0; d < ND; ++d) s = fmaf(qr[d], W1[d * NU + u], s);
  add2[(b << 10) + u] = s + W1b[u] + W2b[u];
}

// W2_k [D][U] f32 -> W2t [U][D] bf16
__global__ void k_w2t(const float* __restrict__ W2, unsigned short* __restrict__ W2t) {
  __shared__ unsigned short tile[64][65];
  int bu = blockIdx.x * 64, bd = blockIdx.y * 64;
  int x = threadIdx.x & 63, y4 = threadIdx.x >> 6;
#pragma unroll
  for (int r = 0; r < 16; ++r) {
    int dl = y4 * 16 + r;
    tile[x][dl] = f2bf(W2[(size_t)(bd + dl) * NU + bu + x]);
  }
  __syncthreads();
#pragma unroll
  for (int r = 0; r < 16; ++r) {
    int ul = y4 * 16 + r;
    W2t[(size_t)(bu + ul) * ND + bd + x] = tile[ul][x];
  }
}

// softmax over T per batch; sums 4 N-tile partials first (deterministic)
__global__ void k_softmax(const float* __restrict__ sp, float* __restrict__ w) {
  __shared__ float redm[4], reds[4];
  int b = blockIdx.x, tid = threadIdx.x;
  float s[8];
  float mx = -1e30f;
#pragma unroll
  for (int i = 0; i < 8; ++i) {
    int t = i * 256 + tid;
    float v = 0.f;
#pragma unroll
    for (int p = 0; p < 4; ++p) v += sp[((size_t)p << 16) + (b << 11) + t];
    s[i] = v;
    mx = fmaxf(mx, v);
  }
#pragma unroll
  for (int o = 1; o < 64; o <<= 1) mx = fmaxf(mx, __shfl_xor(mx, o));
  if ((tid & 63) == 0) redm[tid >> 6] = mx;
  __syncthreads();
  mx = fmaxf(fmaxf(redm[0], redm[1]), fmaxf(redm[2], redm[3]));
  float sum = 0.f;
#pragma unroll
  for (int i = 0; i < 8; ++i) { s[i] = __expf(s[i] - mx); sum += s[i]; }
#pragma unroll
  for (int o = 1; o < 64; o <<= 1) sum += __shfl_xor(sum, o);
  if ((tid & 63) == 0) reds[tid >> 6] = sum;
  __syncthreads();
  float inv = 1.0f / (reds[0] + reds[1] + reds[2] + reds[3]);
#pragma unroll
  for (int i = 0; i < 8; ++i) w[(b << 11) + i * 256 + tid] = s[i] * inv;
}

// context partials: part[tc][b][d] = sum_{t in chunk} w[b][t]*values[b][t][d] (float4)
__global__ void k_context(const float* __restrict__ values, const float* __restrict__ wv,
                          float* __restrict__ part) {
  int d4 = threadIdx.x;                 // 256 threads -> d = d4*4
  int b = blockIdx.y, tc = blockIdx.z;
  const float4* vb = (const float4*)(values + ((size_t)b << 21) + ((size_t)tc << 18)) + d4;
  const float* wb = wv + (b << 11) + (tc << 8);
  float ax = 0.f, ay = 0.f, az = 0.f, aw = 0.f;
#pragma unroll 4
  for (int t = 0; t < 256; ++t) {
    float4 v = vb[(size_t)t << 8];
    float wt = wb[t];
    ax = fmaf(wt, v.x, ax); ay = fmaf(wt, v.y, ay);
    az = fmaf(wt, v.z, az); aw = fmaf(wt, v.w, aw);
  }
  float4* po = (float4*)(part + (((size_t)tc * NB + b) << 10)) + d4;
  *po = make_float4(ax, ay, az, aw);
}

__global__ void k_ctx_reduce(const float* __restrict__ part, float* __restrict__ out) {
  int i = blockIdx.x * 256 + threadIdx.x;  // 32768
  float s = 0.f;
#pragma unroll
  for (int p = 0; p < 8; ++p) s += part[(p << 15) + i];
  out[i] = s;
}

extern "C" void kernel_launch(void* const* d_in, const int* in_sizes, int n_in,
                              void* d_out, int out_size, void* d_ws, size_t ws_size,
                              hipStream_t stream) {
  const float* query  = (const float*)d_in[0];
  const float* values = (const float*)d_in[1];
  const float* W1k    = (const float*)d_in[2];
  const float* W1b    = (const float*)d_in[3];
  const float* W2k    = (const float*)d_in[4];
  const float* W2b    = (const float*)d_in[5];
  const float* Vk     = (const float*)d_in[6];
  // V_b dropped: softmax is shift-invariant.
  float* out = (float*)d_out;
  char* ws = (char*)d_ws;

  size_t off = 0;
  float* add2 = (float*)(ws + off); off += (size_t)NB * NU * 4;          // 128 KB
  float* sp   = (float*)(ws + off); off += (size_t)4 * NM * 4;           // 1 MB
  float* wv   = (float*)(ws + off); off += (size_t)NM * 4;               // 256 KB
  float* ctxp = (float*)(ws + off); off += (size_t)8 * NB * ND * 4;      // 1 MB
  unsigned short* W2t = (unsigned short*)(ws + off); off += (size_t)NU * ND * 2; // 2 MB

  k_qproj<<<dim3(4, 32), 256, 0, stream>>>(query, W1k, W1b, W2b, add2);
  k_w2t<<<dim3(16, 16), 256, 0, stream>>>(W2k, W2t);
  k_score_gemm8<<<dim3(1024), 512, 0, stream>>>(values, W2t, add2, Vk, sp);
  k_softmax<<<dim3(32), 256, 0, stream>>>(sp, wv);
  k_context<<<dim3(1, 32, 8), 256, 0, stream>>>(values, wv, ctxp);
  k_ctx_reduce<<<dim3(128), 256, 0, stream>>>(ctxp, out);
}